// Round 14
// baseline (163.543 us; speedup 1.0000x reference)
//
#include <hip/hip_runtime.h>
#include <math.h>

#define N_LEFTC  5000
#define N_RIGHTC 20000
#define NEDGE    400000
#define MAXD     56        // padded slots per dst; data max degree << 56 (Poisson(20))

typedef __attribute__((ext_vector_type(8))) short bf16x8;
typedef __attribute__((ext_vector_type(4))) float f32x4;
typedef __attribute__((ext_vector_type(4))) unsigned short u16x4;
typedef __attribute__((ext_vector_type(8))) unsigned short u16x8;

__device__ __forceinline__ unsigned short f2bf(float x) {
    unsigned int u = __float_as_uint(x);
    u = (u + 0x7fffu + ((u >> 16) & 1u)) >> 16;
    return (unsigned short)u;
}
__device__ __forceinline__ float bf2f(unsigned short u) {
    return __uint_as_float(((unsigned int)u) << 16);
}

// ---------------------------------------------------------------------------
// bf16 A-fragment (8 elems) from fp32 row-major A
// ---------------------------------------------------------------------------
__device__ __forceinline__ bf16x8 loadA_f32(const float* p) {
    float4 f0 = *(const float4*)p;
    float4 f1 = *(const float4*)(p + 4);
    bf16x8 a;
    a[0] = (short)f2bf(f0.x); a[1] = (short)f2bf(f0.y);
    a[2] = (short)f2bf(f0.z); a[3] = (short)f2bf(f0.w);
    a[4] = (short)f2bf(f1.x); a[5] = (short)f2bf(f1.y);
    a[6] = (short)f2bf(f1.z); a[7] = (short)f2bf(f1.w);
    return a;
}

// ---------------------------------------------------------------------------
// Device GEMM body: C[64 rows @ bid][128] = A @ B (Bp packed fragments)
// ---------------------------------------------------------------------------
template<bool ABF, bool OBF>
__device__ __forceinline__ void gemm_body(const void* __restrict__ Av,
    const unsigned short* __restrict__ Bp, void* __restrict__ Cv, int M,
    int bid, int tid)
{
    const int l  = tid & 63;
    const int w  = tid >> 6;
    const int r0 = bid * 64 + w * 16;
    const int arow = r0 + (l & 15);
    const int kl = (l >> 4) * 8;
    f32x4 acc[8];
    #pragma unroll
    for (int ct = 0; ct < 8; ++ct) acc[ct] = (f32x4){0.f, 0.f, 0.f, 0.f};
    const bool aok = (arow < M);
    #pragma unroll
    for (int ks = 0; ks < 4; ++ks) {
        bf16x8 a = {0, 0, 0, 0, 0, 0, 0, 0};
        if (aok) {
            if (ABF) a = *(const bf16x8*)((const unsigned short*)Av + (size_t)arow * 128 + ks * 32 + kl);
            else     a = loadA_f32((const float*)Av + (size_t)arow * 128 + ks * 32 + kl);
        }
        #pragma unroll
        for (int ct = 0; ct < 8; ++ct) {
            bf16x8 b = *(const bf16x8*)(Bp + (((ks * 8 + ct) * 64 + l) << 3));
            acc[ct] = __builtin_amdgcn_mfma_f32_16x16x32_bf16(a, b, acc[ct], 0, 0, 0);
        }
    }
    const int orow = r0 + (l >> 4) * 4;
    const int oc   = l & 15;
    #pragma unroll
    for (int ct = 0; ct < 8; ++ct) {
        int col = ct * 16 + oc;
        #pragma unroll
        for (int r = 0; r < 4; ++r) {
            if (orow + r < M) {
                float v = acc[ct][r];
                if (OBF) ((unsigned short*)Cv)[(size_t)(orow + r) * 128 + col] = f2bf(v);
                else     ((float*)Cv)[(size_t)(orow + r) * 128 + col] = v;
            }
        }
    }
}

// ---------------------------------------------------------------------------
// Fused: pack_weights (0..447) + cursor init (448..526) + stats/done zero (527)
// ---------------------------------------------------------------------------
__global__ __launch_bounds__(256) void pack_init(const float* __restrict__ Wq,
    const float* __restrict__ Wk, const float* __restrict__ Wv,
    const float* __restrict__ Wout, const float* __restrict__ W2,
    const float* __restrict__ W1, unsigned short* __restrict__ Bp,
    int* __restrict__ cursors, float* __restrict__ stats, int* __restrict__ done)
{
    if (blockIdx.x < 448) {
        int i = blockIdx.x * 256 + threadIdx.x;
        const float* src; int rem;
        if (i < 81920) {
            int m = i >> 14; rem = i & 16383;
            src = (m == 0) ? Wq : (m == 1) ? Wk : (m == 2) ? Wv : (m == 3) ? Wout : W2;
        } else { rem = i - 81920; src = W1; }
        int j  = rem & 7;
        int l  = (rem >> 3) & 63;
        int ct = (rem >> 9) & 7;
        int ks = rem >> 12;
        int k  = ks * 32 + ((l >> 4) << 3) + j;
        int c  = (ct << 4) + (l & 15);
        Bp[i] = f2bf(src[k * 128 + c]);
    } else if (blockIdx.x < 527) {
        int i = (blockIdx.x - 448) * 256 + threadIdx.x;
        if (i < N_RIGHTC) cursors[i] = i * MAXD;
    } else {
        stats[threadIdx.x] = 0.f;
        if (threadIdx.x == 0) *done = 0;
    }
}

// ---------------------------------------------------------------------------
// Fused: padded scatter (0..511) + Q GEMM (512..824) + KV GEMM (825..903)
// Scatter writes ONE 16B record per edge: {ef as 4xbf16 | src u32 | pad}.
// KV GEMM writes interleaved kv rows (one 16B load per edge-lane in attn).
// ---------------------------------------------------------------------------
__global__ __launch_bounds__(256) void scatter_qkv(const int* __restrict__ edst,
    const int* __restrict__ esrc, const float4* __restrict__ ef,
    int* __restrict__ cursors, uint4* __restrict__ rec,
    const float* __restrict__ right, const float* __restrict__ left,
    const unsigned short* __restrict__ BpQ, const unsigned short* __restrict__ BpK,
    const unsigned short* __restrict__ BpV, unsigned short* __restrict__ Q,
    unsigned short* __restrict__ KV)
{
    if (blockIdx.x < 512) {
        for (int i = blockIdx.x * 256 + threadIdx.x; i < NEDGE; i += 512 * 256) {
            int d = edst[i];
            int p = atomicAdd(&cursors[d], 1);
            if (p < d * MAXD + MAXD) {          // OOB guard (degree overflow)
                float4 e = ef[i];
                uint4 r;
                r.x = (unsigned)f2bf(e.x) | ((unsigned)f2bf(e.y) << 16);
                r.y = (unsigned)f2bf(e.z) | ((unsigned)f2bf(e.w) << 16);
                r.z = (unsigned)esrc[i];
                r.w = 0u;
                rec[p] = r;
            }
        }
    } else if (blockIdx.x < 825) {
        gemm_body<false, true>(right, BpQ, Q, N_RIGHTC, blockIdx.x - 512, threadIdx.x);
    } else {
        const int bid = blockIdx.x - 825;
        const int tid = threadIdx.x;
        const int l  = tid & 63;
        const int w  = tid >> 6;
        const int r0 = bid * 64 + w * 16;
        const int arow = r0 + (l & 15);
        const int kl = (l >> 4) * 8;
        f32x4 acck[8], accv[8];
        #pragma unroll
        for (int ct = 0; ct < 8; ++ct) { acck[ct] = (f32x4){0,0,0,0}; accv[ct] = (f32x4){0,0,0,0}; }
        const bool aok = (arow < N_LEFTC);
        #pragma unroll
        for (int ks = 0; ks < 4; ++ks) {
            bf16x8 a = {0, 0, 0, 0, 0, 0, 0, 0};
            if (aok) a = loadA_f32(left + (size_t)arow * 128 + ks * 32 + kl);
            #pragma unroll
            for (int ct = 0; ct < 8; ++ct) {
                int fo = ((ks * 8 + ct) * 64 + l) << 3;
                bf16x8 bk = *(const bf16x8*)(BpK + fo);
                bf16x8 bv = *(const bf16x8*)(BpV + fo);
                acck[ct] = __builtin_amdgcn_mfma_f32_16x16x32_bf16(a, bk, acck[ct], 0, 0, 0);
                accv[ct] = __builtin_amdgcn_mfma_f32_16x16x32_bf16(a, bv, accv[ct], 0, 0, 0);
            }
        }
        const int orow = r0 + (l >> 4) * 4;
        const int oc   = l & 15;
        #pragma unroll
        for (int ct = 0; ct < 8; ++ct) {
            int col = ct * 16 + oc;
            int cb  = ((col >> 2) << 3) + (col & 3);   // interleaved column base
            #pragma unroll
            for (int r = 0; r < 4; ++r) {
                if (orow + r < N_LEFTC) {
                    size_t base = (size_t)(orow + r) * 256 + cb;
                    KV[base]     = f2bf(acck[ct][r]);
                    KV[base + 4] = f2bf(accv[ct][r]);
                }
            }
        }
    }
}

// ---------------------------------------------------------------------------
// Fused edge attention, persistent waves over dsts. e0 = d*MAXD, e1 = cursors[d].
// Halves take [e0,mid)/[mid,e1), 4 edges batched. Per edge-lane ONE 16B kv load;
// edge record (bf16 ef + src) is one 16B broadcast read.
// ---------------------------------------------------------------------------
__global__ __launch_bounds__(256) void attn_kernel(
    const unsigned short* __restrict__ qp, const unsigned short* __restrict__ kvp,
    const uint4* __restrict__ rec, const int* __restrict__ cursors,
    const float* __restrict__ Wke, const float* __restrict__ Wve,
    unsigned short* __restrict__ agg)
{
    const int w    = threadIdx.x >> 6;
    const int l    = threadIdx.x & 63;
    const int half = l >> 5;
    const int hl   = l & 31;
    const int c0   = hl * 4;
    const int kvo  = hl * 8;
    const int gw   = blockIdx.x * 4 + w;
    const int nw   = gridDim.x * 4;

    float wke[4][4], wve[4][4];
    #pragma unroll
    for (int f = 0; f < 4; ++f) {
        float4 a = *(const float4*)(Wke + f * 128 + c0);
        wke[f][0] = a.x; wke[f][1] = a.y; wke[f][2] = a.z; wke[f][3] = a.w;
        float4 b = *(const float4*)(Wve + f * 128 + c0);
        wve[f][0] = b.x; wve[f][1] = b.y; wve[f][2] = b.z; wve[f][3] = b.w;
    }

    for (int d = gw; d < N_RIGHTC; d += nw) {
        u16x4 qu = *(const u16x4*)(qp + (size_t)d * 128 + c0);
        float qv[4] = { bf2f(qu[0]), bf2f(qu[1]), bf2f(qu[2]), bf2f(qu[3]) };

        float tq[4];
        #pragma unroll
        for (int f = 0; f < 4; ++f) {
            float tp = qv[0] * wke[f][0] + qv[1] * wke[f][1]
                     + qv[2] * wke[f][2] + qv[3] * wke[f][3];
            tp += __shfl_xor(tp, 1);
            tp += __shfl_xor(tp, 2);
            tq[f] = tp;
        }

        const int e0 = d * MAXD;
        int e1 = cursors[d];
        if (e1 > e0 + MAXD) e1 = e0 + MAXD;
        const int mid = (e0 + e1 + 1) >> 1;
        const int p0 = half ? mid : e0;
        const int pe = half ? e1 : mid;

        float s = 0.f;
        float av[4]  = {0.f, 0.f, 0.f, 0.f};
        float sef[4] = {0.f, 0.f, 0.f, 0.f};

        for (int p = p0; p < pe; p += 4) {
            int src_[4]; float4 ef_[4]; bool ok_[4];
            #pragma unroll
            for (int b = 0; b < 4; ++b) {
                int idx = p + b;
                ok_[b] = (idx < pe);
                int ii = ok_[b] ? idx : p0;
                uint4 r = rec[ii];
                ef_[b] = make_float4(bf2f((unsigned short)(r.x & 0xffffu)),
                                     bf2f((unsigned short)(r.x >> 16)),
                                     bf2f((unsigned short)(r.y & 0xffffu)),
                                     bf2f((unsigned short)(r.y >> 16)));
                src_[b] = (int)r.z;
            }
            u16x8 kv_[4];
            #pragma unroll
            for (int b = 0; b < 4; ++b)
                kv_[b] = *(const u16x8*)(kvp + (size_t)src_[b] * 256 + kvo);
            #pragma unroll
            for (int b = 0; b < 4; ++b) {
                float pp = qv[0] * bf2f(kv_[b][0]) + qv[1] * bf2f(kv_[b][1])
                         + qv[2] * bf2f(kv_[b][2]) + qv[3] * bf2f(kv_[b][3]);
                pp += __shfl_xor(pp, 1);
                pp += __shfl_xor(pp, 2);
                float4 f = ef_[b];
                float lg = (pp + f.x * tq[0] + f.y * tq[1] + f.z * tq[2] + f.w * tq[3]) * 0.25f;
                float e = ok_[b] ? __expf(lg) : 0.f;
                s += e;
                av[0] += e * bf2f(kv_[b][4]); av[1] += e * bf2f(kv_[b][5]);
                av[2] += e * bf2f(kv_[b][6]); av[3] += e * bf2f(kv_[b][7]);
                sef[0] += e * f.x; sef[1] += e * f.y; sef[2] += e * f.z; sef[3] += e * f.w;
            }
        }
        #pragma unroll
        for (int f = 0; f < 4; ++f) {
            av[0] += sef[f] * wve[f][0]; av[1] += sef[f] * wve[f][1];
            av[2] += sef[f] * wve[f][2]; av[3] += sef[f] * wve[f][3];
        }
        s += __shfl_xor(s, 32);
        #pragma unroll
        for (int j = 0; j < 4; ++j) av[j] += __shfl_xor(av[j], 32);
        if (half == 0) {
            float inv = 1.f / (s + 1e-16f);
            u16x4 o = { f2bf(av[0] * inv), f2bf(av[1] * inv),
                        f2bf(av[2] * inv), f2bf(av[3] * inv) };
            *(u16x4*)(agg + (size_t)d * 128 + c0) = o;
        }
    }
}

// ---------------------------------------------------------------------------
// Fused tail, single dispatch (313 co-resident blocks, spin barrier):
// phase A: out0 = agg @ Wout (+ BN stats, atomic) -> release
// barrier: threadfence + done++ ; spin until done == gridDim.x ; threadfence
// phase B: bn params from stats ; h = relu([bn(out0), right] @ W1 + b1) -> LDS ;
//          out = h @ W2 + b2
// ---------------------------------------------------------------------------
__global__ __launch_bounds__(256) void gemm_fused(const unsigned short* __restrict__ agg,
    const unsigned short* __restrict__ BpO, unsigned short* __restrict__ out0,
    float* __restrict__ stats, int* __restrict__ done,
    const float* __restrict__ right, const float* __restrict__ gamma,
    const float* __restrict__ beta,
    const unsigned short* __restrict__ Bp1, const float* __restrict__ b1,
    const unsigned short* __restrict__ Bp2, const float* __restrict__ b2,
    float* __restrict__ out)
{
    const int M = N_RIGHTC;
    const int tid = threadIdx.x;
    const int l  = tid & 63;
    const int w  = tid >> 6;
    const int r0 = blockIdx.x * 64 + w * 16;
    const int arow = r0 + (l & 15);
    const int kl = (l >> 4) * 8;
    const bool aok = (arow < M);

    __shared__ float sds[256];
    __shared__ unsigned short h[64][136];
    __shared__ float sbn[256];

    // ---------------- phase A: Wout GEMM + BN stats ----------------
    sds[tid] = 0.f;
    __syncthreads();
    f32x4 acc[8];
    #pragma unroll
    for (int ct = 0; ct < 8; ++ct) acc[ct] = (f32x4){0.f, 0.f, 0.f, 0.f};
    #pragma unroll
    for (int ks = 0; ks < 4; ++ks) {
        bf16x8 a = {0, 0, 0, 0, 0, 0, 0, 0};
        if (aok) a = *(const bf16x8*)(agg + (size_t)arow * 128 + ks * 32 + kl);
        #pragma unroll
        for (int ct = 0; ct < 8; ++ct) {
            bf16x8 b = *(const bf16x8*)(BpO + (((ks * 8 + ct) * 64 + l) << 3));
            acc[ct] = __builtin_amdgcn_mfma_f32_16x16x32_bf16(a, b, acc[ct], 0, 0, 0);
        }
    }
    {
        const int orow = r0 + (l >> 4) * 4;
        const int oc   = l & 15;
        #pragma unroll
        for (int ct = 0; ct < 8; ++ct) {
            int col = ct * 16 + oc;
            float cs = 0.f, cq = 0.f;
            #pragma unroll
            for (int r = 0; r < 4; ++r) {
                if (orow + r < M) {
                    float v = acc[ct][r];
                    out0[(size_t)(orow + r) * 128 + col] = f2bf(v);
                    cs += v; cq += v * v;
                }
            }
            atomicAdd(&sds[col], cs);
            atomicAdd(&sds[128 + col], cq);
        }
    }
    __syncthreads();
    atomicAdd(&stats[tid], sds[tid]);

    // ---------------- grid barrier (all blocks co-resident) ----------------
    __threadfence();
    __syncthreads();
    if (tid == 0) {
        atomicAdd(done, 1);
        while (atomicAdd(done, 0) < (int)gridDim.x) {}
    }
    __syncthreads();
    __threadfence();

    // ---------------- phase B: BN apply + MLP ----------------
    if (tid < 128) {
        int c = tid;
        float mean = stats[c] * (1.f / N_RIGHTC);
        float var  = stats[128 + c] * (1.f / N_RIGHTC) - mean * mean;
        float sc   = gamma[c] * rsqrtf(var + 1e-5f);
        sbn[c]       = sc;
        sbn[128 + c] = beta[c] - mean * sc;
    }
    __syncthreads();

    #pragma unroll
    for (int ct = 0; ct < 8; ++ct) acc[ct] = (f32x4){0.f, 0.f, 0.f, 0.f};
    #pragma unroll
    for (int ks = 0; ks < 8; ++ks) {
        bf16x8 a = {0, 0, 0, 0, 0, 0, 0, 0};
        if (aok) {
            if (ks < 4) {
                int k0 = ks * 32 + kl;
                bf16x8 raw = *(const bf16x8*)(out0 + (size_t)arow * 128 + k0);
                #pragma unroll
                for (int j = 0; j < 8; ++j)
                    a[j] = (short)f2bf(bf2f((unsigned short)raw[j]) * sbn[k0 + j] + sbn[128 + k0 + j]);
            } else {
                a = loadA_f32(right + (size_t)arow * 128 + (ks - 4) * 32 + kl);
            }
        }
        #pragma unroll
        for (int ct = 0; ct < 8; ++ct) {
            bf16x8 b = *(const bf16x8*)(Bp1 + (((ks * 8 + ct) * 64 + l) << 3));
            acc[ct] = __builtin_amdgcn_mfma_f32_16x16x32_bf16(a, b, acc[ct], 0, 0, 0);
        }
    }
    {
        const int lr0 = w * 16 + (l >> 4) * 4;
        const int oc  = l & 15;
        #pragma unroll
        for (int ct = 0; ct < 8; ++ct) {
            int col = ct * 16 + oc;
            float bv = b1[col];
            #pragma unroll
            for (int r = 0; r < 4; ++r)
                h[lr0 + r][col] = f2bf(fmaxf(acc[ct][r] + bv, 0.f));
        }
    }
    __syncthreads();
    #pragma unroll
    for (int ct = 0; ct < 8; ++ct) acc[ct] = (f32x4){0.f, 0.f, 0.f, 0.f};
    const int lrow = w * 16 + (l & 15);
    #pragma unroll
    for (int ks = 0; ks < 4; ++ks) {
        bf16x8 a = *(const bf16x8*)&h[lrow][ks * 32 + kl];
        #pragma unroll
        for (int ct = 0; ct < 8; ++ct) {
            bf16x8 b = *(const bf16x8*)(Bp2 + (((ks * 8 + ct) * 64 + l) << 3));
            acc[ct] = __builtin_amdgcn_mfma_f32_16x16x32_bf16(a, b, acc[ct], 0, 0, 0);
        }
    }
    {
        const int orow = r0 + (l >> 4) * 4;
        const int oc   = l & 15;
        #pragma unroll
        for (int ct = 0; ct < 8; ++ct) {
            int col = ct * 16 + oc;
            float bv = b2[col];
            #pragma unroll
            for (int r = 0; r < 4; ++r)
                if (orow + r < M)
                    out[(size_t)(orow + r) * 128 + col] = acc[ct][r] + bv;
        }
    }
}

// ---------------------------------------------------------------------------
// launch
// ---------------------------------------------------------------------------
extern "C" void kernel_launch(void* const* d_in, const int* in_sizes, int n_in,
                              void* d_out, int out_size, void* d_ws, size_t ws_size,
                              hipStream_t stream)
{
    const float* left  = (const float*)d_in[0];
    const float* right = (const float*)d_in[1];
    const float* ef    = (const float*)d_in[2];
    const int*   esrc  = (const int*)d_in[3];
    const int*   edst  = (const int*)d_in[4];
    const float* Wq    = (const float*)d_in[5];
    const float* Wk    = (const float*)d_in[6];
    const float* Wv    = (const float*)d_in[7];
    const float* Wke   = (const float*)d_in[8];
    const float* Wve   = (const float*)d_in[9];
    const float* Wout  = (const float*)d_in[10];
    const float* gamma = (const float*)d_in[11];
    const float* beta  = (const float*)d_in[12];
    const float* W1    = (const float*)d_in[13];
    const float* b1    = (const float*)d_in[14];
    const float* W2    = (const float*)d_in[15];
    const float* b2    = (const float*)d_in[16];
    float* out = (float*)d_out;

    char* ws = (char*)d_ws;
    float* stats   = (float*)(ws + 0);                         //      1,024
    int*   done    = (int*)  (ws + 1024);                      //          4 (pad to 128)
    int*   cursors = (int*)  (ws + 1152);                      //     80,000
    unsigned short* Bp     = (unsigned short*)(ws + 81152);    //    229,376
    unsigned short* qproj  = (unsigned short*)(ws + 310528);   //  5,120,000
    unsigned short* kvproj = (unsigned short*)(ws + 5430528);  //  2,560,000
    unsigned short* agg    = (unsigned short*)(ws + 7990528);  //  5,120,000
    uint4* rec     = (uint4*)(ws + 13110528);                  // 17,920,000 (20000*56*16)
    unsigned short* out0   = (unsigned short*)(ws + 13110528); //  aliases rec (dead after attn)
    // total: 31,030,528 bytes

    pack_init<<<528, 256, 0, stream>>>(Wq, Wk, Wv, Wout, W2, W1, Bp, cursors, stats, done);

    scatter_qkv<<<904, 256, 0, stream>>>(edst, esrc, (const float4*)ef, cursors, rec,
                                         right, left, Bp, Bp + 16384, Bp + 32768,
                                         qproj, kvproj);

    attn_kernel<<<2048, 256, 0, stream>>>(qproj, kvproj, rec, cursors, Wke, Wve, agg);

    gemm_fused<<<313, 256, 0, stream>>>(agg, Bp + 49152, out0, stats, done,
                                        right, gamma, beta,
                                        Bp + 81920, b1, Bp + 65536, b2, out);
}

// Round 15
// 110.901 us; speedup vs baseline: 1.4747x; 1.4747x over previous
//
#include <hip/hip_runtime.h>
#include <math.h>

#define N_LEFTC  5000
#define N_RIGHTC 20000
#define NEDGE    400000
#define MAXD     56        // padded slots per dst; data max degree << 56 (Poisson(20))

typedef __attribute__((ext_vector_type(8))) short bf16x8;
typedef __attribute__((ext_vector_type(4))) float f32x4;
typedef __attribute__((ext_vector_type(4))) unsigned short u16x4;
typedef __attribute__((ext_vector_type(8))) unsigned short u16x8;

__device__ __forceinline__ unsigned short f2bf(float x) {
    unsigned int u = __float_as_uint(x);
    u = (u + 0x7fffu + ((u >> 16) & 1u)) >> 16;
    return (unsigned short)u;
}
__device__ __forceinline__ float bf2f(unsigned short u) {
    return __uint_as_float(((unsigned int)u) << 16);
}

// ---------------------------------------------------------------------------
// bf16 A-fragment (8 elems) from fp32 row-major A
// ---------------------------------------------------------------------------
__device__ __forceinline__ bf16x8 loadA_f32(const float* p) {
    float4 f0 = *(const float4*)p;
    float4 f1 = *(const float4*)(p + 4);
    bf16x8 a;
    a[0] = (short)f2bf(f0.x); a[1] = (short)f2bf(f0.y);
    a[2] = (short)f2bf(f0.z); a[3] = (short)f2bf(f0.w);
    a[4] = (short)f2bf(f1.x); a[5] = (short)f2bf(f1.y);
    a[6] = (short)f2bf(f1.z); a[7] = (short)f2bf(f1.w);
    return a;
}

// ---------------------------------------------------------------------------
// Device GEMM body: C[64 rows @ bid][128] = A @ B (Bp packed fragments)
// ---------------------------------------------------------------------------
template<bool ABF, bool OBF>
__device__ __forceinline__ void gemm_body(const void* __restrict__ Av,
    const unsigned short* __restrict__ Bp, void* __restrict__ Cv, int M,
    int bid, int tid)
{
    const int l  = tid & 63;
    const int w  = tid >> 6;
    const int r0 = bid * 64 + w * 16;
    const int arow = r0 + (l & 15);
    const int kl = (l >> 4) * 8;
    f32x4 acc[8];
    #pragma unroll
    for (int ct = 0; ct < 8; ++ct) acc[ct] = (f32x4){0.f, 0.f, 0.f, 0.f};
    const bool aok = (arow < M);
    #pragma unroll
    for (int ks = 0; ks < 4; ++ks) {
        bf16x8 a = {0, 0, 0, 0, 0, 0, 0, 0};
        if (aok) {
            if (ABF) a = *(const bf16x8*)((const unsigned short*)Av + (size_t)arow * 128 + ks * 32 + kl);
            else     a = loadA_f32((const float*)Av + (size_t)arow * 128 + ks * 32 + kl);
        }
        #pragma unroll
        for (int ct = 0; ct < 8; ++ct) {
            bf16x8 b = *(const bf16x8*)(Bp + (((ks * 8 + ct) * 64 + l) << 3));
            acc[ct] = __builtin_amdgcn_mfma_f32_16x16x32_bf16(a, b, acc[ct], 0, 0, 0);
        }
    }
    const int orow = r0 + (l >> 4) * 4;
    const int oc   = l & 15;
    #pragma unroll
    for (int ct = 0; ct < 8; ++ct) {
        int col = ct * 16 + oc;
        #pragma unroll
        for (int r = 0; r < 4; ++r) {
            if (orow + r < M) {
                float v = acc[ct][r];
                if (OBF) ((unsigned short*)Cv)[(size_t)(orow + r) * 128 + col] = f2bf(v);
                else     ((float*)Cv)[(size_t)(orow + r) * 128 + col] = v;
            }
        }
    }
}

// ---------------------------------------------------------------------------
// Fused: pack_weights (0..447) + cursor init (448..526) + stats zero (527)
// ---------------------------------------------------------------------------
__global__ __launch_bounds__(256) void pack_init(const float* __restrict__ Wq,
    const float* __restrict__ Wk, const float* __restrict__ Wv,
    const float* __restrict__ Wout, const float* __restrict__ W2,
    const float* __restrict__ W1, unsigned short* __restrict__ Bp,
    int* __restrict__ cursors, float* __restrict__ stats)
{
    if (blockIdx.x < 448) {
        int i = blockIdx.x * 256 + threadIdx.x;
        const float* src; int rem;
        if (i < 81920) {
            int m = i >> 14; rem = i & 16383;
            src = (m == 0) ? Wq : (m == 1) ? Wk : (m == 2) ? Wv : (m == 3) ? Wout : W2;
        } else { rem = i - 81920; src = W1; }
        int j  = rem & 7;
        int l  = (rem >> 3) & 63;
        int ct = (rem >> 9) & 7;
        int ks = rem >> 12;
        int k  = ks * 32 + ((l >> 4) << 3) + j;
        int c  = (ct << 4) + (l & 15);
        Bp[i] = f2bf(src[k * 128 + c]);
    } else if (blockIdx.x < 527) {
        int i = (blockIdx.x - 448) * 256 + threadIdx.x;
        if (i < N_RIGHTC) cursors[i] = i * MAXD;
    } else {
        stats[threadIdx.x] = 0.f;
    }
}

// ---------------------------------------------------------------------------
// Fused: padded scatter (0..511) + Q GEMM (512..824) + KV GEMM (825..903)
// Scatter writes ONE 16B record per edge: {ef as 4xbf16 | src u32 | pad}.
// KV GEMM writes interleaved kv rows (one 16B load per edge-lane in attn).
// ---------------------------------------------------------------------------
__global__ __launch_bounds__(256) void scatter_qkv(const int* __restrict__ edst,
    const int* __restrict__ esrc, const float4* __restrict__ ef,
    int* __restrict__ cursors, uint4* __restrict__ rec,
    const float* __restrict__ right, const float* __restrict__ left,
    const unsigned short* __restrict__ BpQ, const unsigned short* __restrict__ BpK,
    const unsigned short* __restrict__ BpV, unsigned short* __restrict__ Q,
    unsigned short* __restrict__ KV)
{
    if (blockIdx.x < 512) {
        for (int i = blockIdx.x * 256 + threadIdx.x; i < NEDGE; i += 512 * 256) {
            int d = edst[i];
            int p = atomicAdd(&cursors[d], 1);
            if (p < d * MAXD + MAXD) {          // OOB guard (degree overflow)
                float4 e = ef[i];
                uint4 r;
                r.x = (unsigned)f2bf(e.x) | ((unsigned)f2bf(e.y) << 16);
                r.y = (unsigned)f2bf(e.z) | ((unsigned)f2bf(e.w) << 16);
                r.z = (unsigned)esrc[i];
                r.w = 0u;
                rec[p] = r;
            }
        }
    } else if (blockIdx.x < 825) {
        gemm_body<false, true>(right, BpQ, Q, N_RIGHTC, blockIdx.x - 512, threadIdx.x);
    } else {
        const int bid = blockIdx.x - 825;
        const int tid = threadIdx.x;
        const int l  = tid & 63;
        const int w  = tid >> 6;
        const int r0 = bid * 64 + w * 16;
        const int arow = r0 + (l & 15);
        const int kl = (l >> 4) * 8;
        f32x4 acck[8], accv[8];
        #pragma unroll
        for (int ct = 0; ct < 8; ++ct) { acck[ct] = (f32x4){0,0,0,0}; accv[ct] = (f32x4){0,0,0,0}; }
        const bool aok = (arow < N_LEFTC);
        #pragma unroll
        for (int ks = 0; ks < 4; ++ks) {
            bf16x8 a = {0, 0, 0, 0, 0, 0, 0, 0};
            if (aok) a = loadA_f32(left + (size_t)arow * 128 + ks * 32 + kl);
            #pragma unroll
            for (int ct = 0; ct < 8; ++ct) {
                int fo = ((ks * 8 + ct) * 64 + l) << 3;
                bf16x8 bk = *(const bf16x8*)(BpK + fo);
                bf16x8 bv = *(const bf16x8*)(BpV + fo);
                acck[ct] = __builtin_amdgcn_mfma_f32_16x16x32_bf16(a, bk, acck[ct], 0, 0, 0);
                accv[ct] = __builtin_amdgcn_mfma_f32_16x16x32_bf16(a, bv, accv[ct], 0, 0, 0);
            }
        }
        const int orow = r0 + (l >> 4) * 4;
        const int oc   = l & 15;
        #pragma unroll
        for (int ct = 0; ct < 8; ++ct) {
            int col = ct * 16 + oc;
            int cb  = ((col >> 2) << 3) + (col & 3);   // interleaved column base
            #pragma unroll
            for (int r = 0; r < 4; ++r) {
                if (orow + r < N_LEFTC) {
                    size_t base = (size_t)(orow + r) * 256 + cb;
                    KV[base]     = f2bf(acck[ct][r]);
                    KV[base + 4] = f2bf(accv[ct][r]);
                }
            }
        }
    }
}

// ---------------------------------------------------------------------------
// Fused edge attention, persistent waves over dsts. e0 = d*MAXD, e1 = cursors[d].
// Halves take [e0,mid)/[mid,e1), 4 edges batched. Per edge-lane ONE 16B kv load;
// edge record (bf16 ef + src) is one 16B broadcast read.
// ---------------------------------------------------------------------------
__global__ __launch_bounds__(256) void attn_kernel(
    const unsigned short* __restrict__ qp, const unsigned short* __restrict__ kvp,
    const uint4* __restrict__ rec, const int* __restrict__ cursors,
    const float* __restrict__ Wke, const float* __restrict__ Wve,
    unsigned short* __restrict__ agg)
{
    const int w    = threadIdx.x >> 6;
    const int l    = threadIdx.x & 63;
    const int half = l >> 5;
    const int hl   = l & 31;
    const int c0   = hl * 4;
    const int kvo  = hl * 8;
    const int gw   = blockIdx.x * 4 + w;
    const int nw   = gridDim.x * 4;

    float wke[4][4], wve[4][4];
    #pragma unroll
    for (int f = 0; f < 4; ++f) {
        float4 a = *(const float4*)(Wke + f * 128 + c0);
        wke[f][0] = a.x; wke[f][1] = a.y; wke[f][2] = a.z; wke[f][3] = a.w;
        float4 b = *(const float4*)(Wve + f * 128 + c0);
        wve[f][0] = b.x; wve[f][1] = b.y; wve[f][2] = b.z; wve[f][3] = b.w;
    }

    for (int d = gw; d < N_RIGHTC; d += nw) {
        u16x4 qu = *(const u16x4*)(qp + (size_t)d * 128 + c0);
        float qv[4] = { bf2f(qu[0]), bf2f(qu[1]), bf2f(qu[2]), bf2f(qu[3]) };

        float tq[4];
        #pragma unroll
        for (int f = 0; f < 4; ++f) {
            float tp = qv[0] * wke[f][0] + qv[1] * wke[f][1]
                     + qv[2] * wke[f][2] + qv[3] * wke[f][3];
            tp += __shfl_xor(tp, 1);
            tp += __shfl_xor(tp, 2);
            tq[f] = tp;
        }

        const int e0 = d * MAXD;
        int e1 = cursors[d];
        if (e1 > e0 + MAXD) e1 = e0 + MAXD;
        const int mid = (e0 + e1 + 1) >> 1;
        const int p0 = half ? mid : e0;
        const int pe = half ? e1 : mid;

        float s = 0.f;
        float av[4]  = {0.f, 0.f, 0.f, 0.f};
        float sef[4] = {0.f, 0.f, 0.f, 0.f};

        for (int p = p0; p < pe; p += 4) {
            int src_[4]; float4 ef_[4]; bool ok_[4];
            #pragma unroll
            for (int b = 0; b < 4; ++b) {
                int idx = p + b;
                ok_[b] = (idx < pe);
                int ii = ok_[b] ? idx : p0;
                uint4 r = rec[ii];
                ef_[b] = make_float4(bf2f((unsigned short)(r.x & 0xffffu)),
                                     bf2f((unsigned short)(r.x >> 16)),
                                     bf2f((unsigned short)(r.y & 0xffffu)),
                                     bf2f((unsigned short)(r.y >> 16)));
                src_[b] = (int)r.z;
            }
            u16x8 kv_[4];
            #pragma unroll
            for (int b = 0; b < 4; ++b)
                kv_[b] = *(const u16x8*)(kvp + (size_t)src_[b] * 256 + kvo);
            #pragma unroll
            for (int b = 0; b < 4; ++b) {
                float pp = qv[0] * bf2f(kv_[b][0]) + qv[1] * bf2f(kv_[b][1])
                         + qv[2] * bf2f(kv_[b][2]) + qv[3] * bf2f(kv_[b][3]);
                pp += __shfl_xor(pp, 1);
                pp += __shfl_xor(pp, 2);
                float4 f = ef_[b];
                float lg = (pp + f.x * tq[0] + f.y * tq[1] + f.z * tq[2] + f.w * tq[3]) * 0.25f;
                float e = ok_[b] ? __expf(lg) : 0.f;
                s += e;
                av[0] += e * bf2f(kv_[b][4]); av[1] += e * bf2f(kv_[b][5]);
                av[2] += e * bf2f(kv_[b][6]); av[3] += e * bf2f(kv_[b][7]);
                sef[0] += e * f.x; sef[1] += e * f.y; sef[2] += e * f.z; sef[3] += e * f.w;
            }
        }
        #pragma unroll
        for (int f = 0; f < 4; ++f) {
            av[0] += sef[f] * wve[f][0]; av[1] += sef[f] * wve[f][1];
            av[2] += sef[f] * wve[f][2]; av[3] += sef[f] * wve[f][3];
        }
        s += __shfl_xor(s, 32);
        #pragma unroll
        for (int j = 0; j < 4; ++j) av[j] += __shfl_xor(av[j], 32);
        if (half == 0) {
            float inv = 1.f / (s + 1e-16f);
            u16x4 o = { f2bf(av[0] * inv), f2bf(av[1] * inv),
                        f2bf(av[2] * inv), f2bf(av[3] * inv) };
            *(u16x4*)(agg + (size_t)d * 128 + c0) = o;
        }
    }
}

// ---------------------------------------------------------------------------
// Wout GEMM (agg bf16 -> out0 bf16) with fused BN statistics (sum, sumsq)
// ---------------------------------------------------------------------------
__global__ __launch_bounds__(256) void gemm_out0(const unsigned short* __restrict__ A,
    const unsigned short* __restrict__ Bp, unsigned short* __restrict__ C,
    float* __restrict__ stats, int M)
{
    __shared__ float sds[256];
    sds[threadIdx.x] = 0.f;
    __syncthreads();

    const int l  = threadIdx.x & 63;
    const int w  = threadIdx.x >> 6;
    const int r0 = blockIdx.x * 64 + w * 16;
    const int arow = r0 + (l & 15);
    const int kl = (l >> 4) * 8;
    f32x4 acc[8];
    #pragma unroll
    for (int ct = 0; ct < 8; ++ct) acc[ct] = (f32x4){0.f, 0.f, 0.f, 0.f};
    const bool aok = (arow < M);
    #pragma unroll
    for (int ks = 0; ks < 4; ++ks) {
        bf16x8 a = {0, 0, 0, 0, 0, 0, 0, 0};
        if (aok) a = *(const bf16x8*)(A + (size_t)arow * 128 + ks * 32 + kl);
        #pragma unroll
        for (int ct = 0; ct < 8; ++ct) {
            bf16x8 b = *(const bf16x8*)(Bp + (((ks * 8 + ct) * 64 + l) << 3));
            acc[ct] = __builtin_amdgcn_mfma_f32_16x16x32_bf16(a, b, acc[ct], 0, 0, 0);
        }
    }
    const int orow = r0 + (l >> 4) * 4;
    const int oc   = l & 15;
    #pragma unroll
    for (int ct = 0; ct < 8; ++ct) {
        int col = ct * 16 + oc;
        float cs = 0.f, cq = 0.f;
        #pragma unroll
        for (int r = 0; r < 4; ++r) {
            if (orow + r < M) {
                float v = acc[ct][r];
                C[(size_t)(orow + r) * 128 + col] = f2bf(v);
                cs += v; cq += v * v;
            }
        }
        atomicAdd(&sds[col], cs);
        atomicAdd(&sds[128 + col], cq);
    }
    __syncthreads();
    atomicAdd(&stats[threadIdx.x], sds[threadIdx.x]);
}

// ---------------------------------------------------------------------------
// Fused tail: bn params from stats (in-block) ;
// h = relu([bn(out0), right] @ W1 + b1) -> LDS ; out = h @ W2 + b2
// ---------------------------------------------------------------------------
__global__ __launch_bounds__(256) void gemm_tail(const unsigned short* __restrict__ A1,
    const float* __restrict__ A2, const float* __restrict__ stats,
    const float* __restrict__ gamma, const float* __restrict__ beta,
    const unsigned short* __restrict__ Bp1, const float* __restrict__ b1,
    const unsigned short* __restrict__ Bp2, const float* __restrict__ b2,
    float* __restrict__ out, int M)
{
    __shared__ unsigned short h[64][136];
    __shared__ float sbn[256];
    if (threadIdx.x < 128) {
        int c = threadIdx.x;
        float mean = stats[c] * (1.f / N_RIGHTC);
        float var  = stats[128 + c] * (1.f / N_RIGHTC) - mean * mean;
        float sc   = gamma[c] * rsqrtf(var + 1e-5f);
        sbn[c]       = sc;
        sbn[128 + c] = beta[c] - mean * sc;
    }
    __syncthreads();

    const int l  = threadIdx.x & 63;
    const int w  = threadIdx.x >> 6;
    const int r0 = blockIdx.x * 64 + w * 16;
    const int arow = r0 + (l & 15);
    const int kl = (l >> 4) * 8;
    f32x4 acc[8];
    #pragma unroll
    for (int ct = 0; ct < 8; ++ct) acc[ct] = (f32x4){0.f, 0.f, 0.f, 0.f};
    const bool aok = (arow < M);
    #pragma unroll
    for (int ks = 0; ks < 8; ++ks) {
        bf16x8 a = {0, 0, 0, 0, 0, 0, 0, 0};
        if (aok) {
            if (ks < 4) {
                int k0 = ks * 32 + kl;
                bf16x8 raw = *(const bf16x8*)(A1 + (size_t)arow * 128 + k0);
                #pragma unroll
                for (int j = 0; j < 8; ++j)
                    a[j] = (short)f2bf(bf2f((unsigned short)raw[j]) * sbn[k0 + j] + sbn[128 + k0 + j]);
            } else {
                a = loadA_f32(A2 + (size_t)arow * 128 + (ks - 4) * 32 + kl);
            }
        }
        #pragma unroll
        for (int ct = 0; ct < 8; ++ct) {
            bf16x8 b = *(const bf16x8*)(Bp1 + (((ks * 8 + ct) * 64 + l) << 3));
            acc[ct] = __builtin_amdgcn_mfma_f32_16x16x32_bf16(a, b, acc[ct], 0, 0, 0);
        }
    }
    {
        const int lr0 = w * 16 + (l >> 4) * 4;
        const int oc  = l & 15;
        #pragma unroll
        for (int ct = 0; ct < 8; ++ct) {
            int col = ct * 16 + oc;
            float bv = b1[col];
            #pragma unroll
            for (int r = 0; r < 4; ++r)
                h[lr0 + r][col] = f2bf(fmaxf(acc[ct][r] + bv, 0.f));
        }
    }
    __syncthreads();
    #pragma unroll
    for (int ct = 0; ct < 8; ++ct) acc[ct] = (f32x4){0.f, 0.f, 0.f, 0.f};
    const int lrow = w * 16 + (l & 15);
    #pragma unroll
    for (int ks = 0; ks < 4; ++ks) {
        bf16x8 a = *(const bf16x8*)&h[lrow][ks * 32 + kl];
        #pragma unroll
        for (int ct = 0; ct < 8; ++ct) {
            bf16x8 b = *(const bf16x8*)(Bp2 + (((ks * 8 + ct) * 64 + l) << 3));
            acc[ct] = __builtin_amdgcn_mfma_f32_16x16x32_bf16(a, b, acc[ct], 0, 0, 0);
        }
    }
    const int orow = r0 + (l >> 4) * 4;
    const int oc   = l & 15;
    #pragma unroll
    for (int ct = 0; ct < 8; ++ct) {
        int col = ct * 16 + oc;
        float bv = b2[col];
        #pragma unroll
        for (int r = 0; r < 4; ++r)
            if (orow + r < M)
                out[(size_t)(orow + r) * 128 + col] = acc[ct][r] + bv;
    }
}

// ---------------------------------------------------------------------------
// launch
// ---------------------------------------------------------------------------
extern "C" void kernel_launch(void* const* d_in, const int* in_sizes, int n_in,
                              void* d_out, int out_size, void* d_ws, size_t ws_size,
                              hipStream_t stream)
{
    const float* left  = (const float*)d_in[0];
    const float* right = (const float*)d_in[1];
    const float* ef    = (const float*)d_in[2];
    const int*   esrc  = (const int*)d_in[3];
    const int*   edst  = (const int*)d_in[4];
    const float* Wq    = (const float*)d_in[5];
    const float* Wk    = (const float*)d_in[6];
    const float* Wv    = (const float*)d_in[7];
    const float* Wke   = (const float*)d_in[8];
    const float* Wve   = (const float*)d_in[9];
    const float* Wout  = (const float*)d_in[10];
    const float* gamma = (const float*)d_in[11];
    const float* beta  = (const float*)d_in[12];
    const float* W1    = (const float*)d_in[13];
    const float* b1    = (const float*)d_in[14];
    const float* W2    = (const float*)d_in[15];
    const float* b2    = (const float*)d_in[16];
    float* out = (float*)d_out;

    char* ws = (char*)d_ws;
    float* stats   = (float*)(ws + 0);                         //      1,024
    int*   cursors = (int*)  (ws + 1024);                      //     80,000
    unsigned short* Bp     = (unsigned short*)(ws + 81024);    //    229,376
    unsigned short* qproj  = (unsigned short*)(ws + 310400);   //  5,120,000
    unsigned short* kvproj = (unsigned short*)(ws + 5430400);  //  2,560,000
    unsigned short* agg    = (unsigned short*)(ws + 7990400);  //  5,120,000
    uint4* rec     = (uint4*)(ws + 13110400);                  // 17,920,000 (20000*56*16)
    unsigned short* out0   = (unsigned short*)(ws + 13110400); //  aliases rec (dead after attn)
    // total: 31,030,400 bytes

    pack_init<<<528, 256, 0, stream>>>(Wq, Wk, Wv, Wout, W2, W1, Bp, cursors, stats);

    scatter_qkv<<<904, 256, 0, stream>>>(edst, esrc, (const float4*)ef, cursors, rec,
                                         right, left, Bp, Bp + 16384, Bp + 32768,
                                         qproj, kvproj);

    attn_kernel<<<2048, 256, 0, stream>>>(qproj, kvproj, rec, cursors, Wke, Wve, agg);

    gemm_out0<<<(N_RIGHTC + 63) / 64, 256, 0, stream>>>(agg, Bp + 49152, out0, stats, N_RIGHTC);

    gemm_tail<<<(N_RIGHTC + 63) / 64, 256, 0, stream>>>(out0, right, stats, gamma, beta,
                                                        Bp + 81920, b1, Bp + 65536, b2,
                                                        out, N_RIGHTC);
}

// Round 17
// 110.411 us; speedup vs baseline: 1.4812x; 1.0044x over previous
//
#include <hip/hip_runtime.h>
#include <math.h>

#define N_LEFTC  5000
#define N_RIGHTC 20000
#define NEDGE    400000
#define MAXD     56        // padded slots per dst; data max degree << 56 (Poisson(20))

typedef __attribute__((ext_vector_type(8))) short bf16x8;
typedef __attribute__((ext_vector_type(4))) float f32x4;
typedef __attribute__((ext_vector_type(4))) unsigned short u16x4;
typedef __attribute__((ext_vector_type(8))) unsigned short u16x8;

__device__ __forceinline__ unsigned short f2bf(float x) {
    unsigned int u = __float_as_uint(x);
    u = (u + 0x7fffu + ((u >> 16) & 1u)) >> 16;
    return (unsigned short)u;
}
__device__ __forceinline__ float bf2f(unsigned short u) {
    return __uint_as_float(((unsigned int)u) << 16);
}

// ---------------------------------------------------------------------------
// bf16 A-fragment (8 elems) from fp32 row-major A
// ---------------------------------------------------------------------------
__device__ __forceinline__ bf16x8 loadA_f32(const float* p) {
    float4 f0 = *(const float4*)p;
    float4 f1 = *(const float4*)(p + 4);
    bf16x8 a;
    a[0] = (short)f2bf(f0.x); a[1] = (short)f2bf(f0.y);
    a[2] = (short)f2bf(f0.z); a[3] = (short)f2bf(f0.w);
    a[4] = (short)f2bf(f1.x); a[5] = (short)f2bf(f1.y);
    a[6] = (short)f2bf(f1.z); a[7] = (short)f2bf(f1.w);
    return a;
}

// ---------------------------------------------------------------------------
// Device GEMM body: C[64 rows @ bid][128] = A @ B (Bp packed fragments)
// ---------------------------------------------------------------------------
template<bool ABF, bool OBF>
__device__ __forceinline__ void gemm_body(const void* __restrict__ Av,
    const unsigned short* __restrict__ Bp, void* __restrict__ Cv, int M,
    int bid, int tid)
{
    const int l  = tid & 63;
    const int w  = tid >> 6;
    const int r0 = bid * 64 + w * 16;
    const int arow = r0 + (l & 15);
    const int kl = (l >> 4) * 8;
    f32x4 acc[8];
    #pragma unroll
    for (int ct = 0; ct < 8; ++ct) acc[ct] = (f32x4){0.f, 0.f, 0.f, 0.f};
    const bool aok = (arow < M);
    #pragma unroll
    for (int ks = 0; ks < 4; ++ks) {
        bf16x8 a = {0, 0, 0, 0, 0, 0, 0, 0};
        if (aok) {
            if (ABF) a = *(const bf16x8*)((const unsigned short*)Av + (size_t)arow * 128 + ks * 32 + kl);
            else     a = loadA_f32((const float*)Av + (size_t)arow * 128 + ks * 32 + kl);
        }
        #pragma unroll
        for (int ct = 0; ct < 8; ++ct) {
            bf16x8 b = *(const bf16x8*)(Bp + (((ks * 8 + ct) * 64 + l) << 3));
            acc[ct] = __builtin_amdgcn_mfma_f32_16x16x32_bf16(a, b, acc[ct], 0, 0, 0);
        }
    }
    const int orow = r0 + (l >> 4) * 4;
    const int oc   = l & 15;
    #pragma unroll
    for (int ct = 0; ct < 8; ++ct) {
        int col = ct * 16 + oc;
        #pragma unroll
        for (int r = 0; r < 4; ++r) {
            if (orow + r < M) {
                float v = acc[ct][r];
                if (OBF) ((unsigned short*)Cv)[(size_t)(orow + r) * 128 + col] = f2bf(v);
                else     ((float*)Cv)[(size_t)(orow + r) * 128 + col] = v;
            }
        }
    }
}

// ---------------------------------------------------------------------------
// Fused: pack_weights (0..447) + cursor init (448..526) + stats zero (527)
// ---------------------------------------------------------------------------
__global__ __launch_bounds__(256) void pack_init(const float* __restrict__ Wq,
    const float* __restrict__ Wk, const float* __restrict__ Wv,
    const float* __restrict__ Wout, const float* __restrict__ W2,
    const float* __restrict__ W1, unsigned short* __restrict__ Bp,
    int* __restrict__ cursors, float* __restrict__ stats)
{
    if (blockIdx.x < 448) {
        int i = blockIdx.x * 256 + threadIdx.x;
        const float* src; int rem;
        if (i < 81920) {
            int m = i >> 14; rem = i & 16383;
            src = (m == 0) ? Wq : (m == 1) ? Wk : (m == 2) ? Wv : (m == 3) ? Wout : W2;
        } else { rem = i - 81920; src = W1; }
        int j  = rem & 7;
        int l  = (rem >> 3) & 63;
        int ct = (rem >> 9) & 7;
        int ks = rem >> 12;
        int k  = ks * 32 + ((l >> 4) << 3) + j;
        int c  = (ct << 4) + (l & 15);
        Bp[i] = f2bf(src[k * 128 + c]);
    } else if (blockIdx.x < 527) {
        int i = (blockIdx.x - 448) * 256 + threadIdx.x;
        if (i < N_RIGHTC) cursors[i] = i * MAXD;
    } else {
        stats[threadIdx.x] = 0.f;
    }
}

// ---------------------------------------------------------------------------
// Fused: padded scatter (0..511) + Q GEMM (512..824) + KV GEMM (825..903)
// Scatter writes ONE 16B record per edge: {ef as 4xbf16 | src u32 | pad}.
// KV GEMM writes interleaved kv rows (one 16B load per edge-lane in attn).
// ---------------------------------------------------------------------------
__global__ __launch_bounds__(256) void scatter_qkv(const int* __restrict__ edst,
    const int* __restrict__ esrc, const float4* __restrict__ ef,
    int* __restrict__ cursors, uint4* __restrict__ rec,
    const float* __restrict__ right, const float* __restrict__ left,
    const unsigned short* __restrict__ BpQ, const unsigned short* __restrict__ BpK,
    const unsigned short* __restrict__ BpV, unsigned short* __restrict__ Q,
    unsigned short* __restrict__ KV)
{
    if (blockIdx.x < 512) {
        for (int i = blockIdx.x * 256 + threadIdx.x; i < NEDGE; i += 512 * 256) {
            int d = edst[i];
            int p = atomicAdd(&cursors[d], 1);
            if (p < d * MAXD + MAXD) {          // OOB guard (degree overflow)
                float4 e = ef[i];
                uint4 r;
                r.x = (unsigned)f2bf(e.x) | ((unsigned)f2bf(e.y) << 16);
                r.y = (unsigned)f2bf(e.z) | ((unsigned)f2bf(e.w) << 16);
                r.z = (unsigned)esrc[i];
                r.w = 0u;
                rec[p] = r;
            }
        }
    } else if (blockIdx.x < 825) {
        gemm_body<false, true>(right, BpQ, Q, N_RIGHTC, blockIdx.x - 512, threadIdx.x);
    } else {
        const int bid = blockIdx.x - 825;
        const int tid = threadIdx.x;
        const int l  = tid & 63;
        const int w  = tid >> 6;
        const int r0 = bid * 64 + w * 16;
        const int arow = r0 + (l & 15);
        const int kl = (l >> 4) * 8;
        f32x4 acck[8], accv[8];
        #pragma unroll
        for (int ct = 0; ct < 8; ++ct) { acck[ct] = (f32x4){0,0,0,0}; accv[ct] = (f32x4){0,0,0,0}; }
        const bool aok = (arow < N_LEFTC);
        #pragma unroll
        for (int ks = 0; ks < 4; ++ks) {
            bf16x8 a = {0, 0, 0, 0, 0, 0, 0, 0};
            if (aok) a = loadA_f32(left + (size_t)arow * 128 + ks * 32 + kl);
            #pragma unroll
            for (int ct = 0; ct < 8; ++ct) {
                int fo = ((ks * 8 + ct) * 64 + l) << 3;
                bf16x8 bk = *(const bf16x8*)(BpK + fo);
                bf16x8 bv = *(const bf16x8*)(BpV + fo);
                acck[ct] = __builtin_amdgcn_mfma_f32_16x16x32_bf16(a, bk, acck[ct], 0, 0, 0);
                accv[ct] = __builtin_amdgcn_mfma_f32_16x16x32_bf16(a, bv, accv[ct], 0, 0, 0);
            }
        }
        const int orow = r0 + (l >> 4) * 4;
        const int oc   = l & 15;
        #pragma unroll
        for (int ct = 0; ct < 8; ++ct) {
            int col = ct * 16 + oc;
            int cb  = ((col >> 2) << 3) + (col & 3);   // interleaved column base
            #pragma unroll
            for (int r = 0; r < 4; ++r) {
                if (orow + r < N_LEFTC) {
                    size_t base = (size_t)(orow + r) * 256 + cb;
                    KV[base]     = f2bf(acck[ct][r]);
                    KV[base + 4] = f2bf(accv[ct][r]);
                }
            }
        }
    }
}

// ---------------------------------------------------------------------------
// Fused edge attention, persistent waves over dsts. e0 = d*MAXD, e1 = cursors[d].
// Halves take [e0,mid)/[mid,e1), 4 edges batched. Per edge-lane ONE 16B kv load;
// edge record (bf16 ef + src) is one 16B broadcast read.
// ---------------------------------------------------------------------------
__global__ __launch_bounds__(256) void attn_kernel(
    const unsigned short* __restrict__ qp, const unsigned short* __restrict__ kvp,
    const uint4* __restrict__ rec, const int* __restrict__ cursors,
    const float* __restrict__ Wke, const float* __restrict__ Wve,
    unsigned short* __restrict__ agg)
{
    const int w    = threadIdx.x >> 6;
    const int l    = threadIdx.x & 63;
    const int half = l >> 5;
    const int hl   = l & 31;
    const int c0   = hl * 4;
    const int kvo  = hl * 8;
    const int gw   = blockIdx.x * 4 + w;
    const int nw   = gridDim.x * 4;

    float wke[4][4], wve[4][4];
    #pragma unroll
    for (int f = 0; f < 4; ++f) {
        float4 a = *(const float4*)(Wke + f * 128 + c0);
        wke[f][0] = a.x; wke[f][1] = a.y; wke[f][2] = a.z; wke[f][3] = a.w;
        float4 b = *(const float4*)(Wve + f * 128 + c0);
        wve[f][0] = b.x; wve[f][1] = b.y; wve[f][2] = b.z; wve[f][3] = b.w;
    }

    for (int d = gw; d < N_RIGHTC; d += nw) {
        u16x4 qu = *(const u16x4*)(qp + (size_t)d * 128 + c0);
        float qv[4] = { bf2f(qu[0]), bf2f(qu[1]), bf2f(qu[2]), bf2f(qu[3]) };

        float tq[4];
        #pragma unroll
        for (int f = 0; f < 4; ++f) {
            float tp = qv[0] * wke[f][0] + qv[1] * wke[f][1]
                     + qv[2] * wke[f][2] + qv[3] * wke[f][3];
            tp += __shfl_xor(tp, 1);
            tp += __shfl_xor(tp, 2);
            tq[f] = tp;
        }

        const int e0 = d * MAXD;
        int e1 = cursors[d];
        if (e1 > e0 + MAXD) e1 = e0 + MAXD;
        const int mid = (e0 + e1 + 1) >> 1;
        const int p0 = half ? mid : e0;
        const int pe = half ? e1 : mid;

        float s = 0.f;
        float av[4]  = {0.f, 0.f, 0.f, 0.f};
        float sef[4] = {0.f, 0.f, 0.f, 0.f};

        for (int p = p0; p < pe; p += 4) {
            int src_[4]; float4 ef_[4]; bool ok_[4];
            #pragma unroll
            for (int b = 0; b < 4; ++b) {
                int idx = p + b;
                ok_[b] = (idx < pe);
                int ii = ok_[b] ? idx : p0;
                uint4 r = rec[ii];
                ef_[b] = make_float4(bf2f((unsigned short)(r.x & 0xffffu)),
                                     bf2f((unsigned short)(r.x >> 16)),
                                     bf2f((unsigned short)(r.y & 0xffffu)),
                                     bf2f((unsigned short)(r.y >> 16)));
                src_[b] = (int)r.z;
            }
            u16x8 kv_[4];
            #pragma unroll
            for (int b = 0; b < 4; ++b)
                kv_[b] = *(const u16x8*)(kvp + (size_t)src_[b] * 256 + kvo);
            #pragma unroll
            for (int b = 0; b < 4; ++b) {
                float pp = qv[0] * bf2f(kv_[b][0]) + qv[1] * bf2f(kv_[b][1])
                         + qv[2] * bf2f(kv_[b][2]) + qv[3] * bf2f(kv_[b][3]);
                pp += __shfl_xor(pp, 1);
                pp += __shfl_xor(pp, 2);
                float4 f = ef_[b];
                float lg = (pp + f.x * tq[0] + f.y * tq[1] + f.z * tq[2] + f.w * tq[3]) * 0.25f;
                float e = ok_[b] ? __expf(lg) : 0.f;
                s += e;
                av[0] += e * bf2f(kv_[b][4]); av[1] += e * bf2f(kv_[b][5]);
                av[2] += e * bf2f(kv_[b][6]); av[3] += e * bf2f(kv_[b][7]);
                sef[0] += e * f.x; sef[1] += e * f.y; sef[2] += e * f.z; sef[3] += e * f.w;
            }
        }
        #pragma unroll
        for (int f = 0; f < 4; ++f) {
            av[0] += sef[f] * wve[f][0]; av[1] += sef[f] * wve[f][1];
            av[2] += sef[f] * wve[f][2]; av[3] += sef[f] * wve[f][3];
        }
        s += __shfl_xor(s, 32);
        #pragma unroll
        for (int j = 0; j < 4; ++j) av[j] += __shfl_xor(av[j], 32);
        if (half == 0) {
            float inv = 1.f / (s + 1e-16f);
            u16x4 o = { f2bf(av[0] * inv), f2bf(av[1] * inv),
                        f2bf(av[2] * inv), f2bf(av[3] * inv) };
            *(u16x4*)(agg + (size_t)d * 128 + c0) = o;
        }
    }
}

// ---------------------------------------------------------------------------
// Wout GEMM (agg bf16 -> out0 bf16) with fused BN statistics (sum, sumsq)
// ---------------------------------------------------------------------------
__global__ __launch_bounds__(256) void gemm_out0(const unsigned short* __restrict__ A,
    const unsigned short* __restrict__ Bp, unsigned short* __restrict__ C,
    float* __restrict__ stats, int M)
{
    __shared__ float sds[256];
    sds[threadIdx.x] = 0.f;
    __syncthreads();

    const int l  = threadIdx.x & 63;
    const int w  = threadIdx.x >> 6;
    const int r0 = blockIdx.x * 64 + w * 16;
    const int arow = r0 + (l & 15);
    const int kl = (l >> 4) * 8;
    f32x4 acc[8];
    #pragma unroll
    for (int ct = 0; ct < 8; ++ct) acc[ct] = (f32x4){0.f, 0.f, 0.f, 0.f};
    const bool aok = (arow < M);
    #pragma unroll
    for (int ks = 0; ks < 4; ++ks) {
        bf16x8 a = {0, 0, 0, 0, 0, 0, 0, 0};
        if (aok) a = *(const bf16x8*)(A + (size_t)arow * 128 + ks * 32 + kl);
        #pragma unroll
        for (int ct = 0; ct < 8; ++ct) {
            bf16x8 b = *(const bf16x8*)(Bp + (((ks * 8 + ct) * 64 + l) << 3));
            acc[ct] = __builtin_amdgcn_mfma_f32_16x16x32_bf16(a, b, acc[ct], 0, 0, 0);
        }
    }
    const int orow = r0 + (l >> 4) * 4;
    const int oc   = l & 15;
    #pragma unroll
    for (int ct = 0; ct < 8; ++ct) {
        int col = ct * 16 + oc;
        float cs = 0.f, cq = 0.f;
        #pragma unroll
        for (int r = 0; r < 4; ++r) {
            if (orow + r < M) {
                float v = acc[ct][r];
                C[(size_t)(orow + r) * 128 + col] = f2bf(v);
                cs += v; cq += v * v;
            }
        }
        atomicAdd(&sds[col], cs);
        atomicAdd(&sds[128 + col], cq);
    }
    __syncthreads();
    atomicAdd(&stats[threadIdx.x], sds[threadIdx.x]);
}

// ---------------------------------------------------------------------------
// Fused tail: bn params from stats (in-block) ;
// h = relu([bn(out0), right] @ W1 + b1) -> LDS ; out = h @ W2 + b2
// ---------------------------------------------------------------------------
__global__ __launch_bounds__(256) void gemm_tail(const unsigned short* __restrict__ A1,
    const float* __restrict__ A2, const float* __restrict__ stats,
    const float* __restrict__ gamma, const float* __restrict__ beta,
    const unsigned short* __restrict__ Bp1, const float* __restrict__ b1,
    const unsigned short* __restrict__ Bp2, const float* __restrict__ b2,
    float* __restrict__ out, int M)
{
    __shared__ unsigned short h[64][136];
    __shared__ float sbn[256];
    if (threadIdx.x < 128) {
        int c = threadIdx.x;
        float mean = stats[c] * (1.f / N_RIGHTC);
        float var  = stats[128 + c] * (1.f / N_RIGHTC) - mean * mean;
        float sc   = gamma[c] * rsqrtf(var + 1e-5f);
        sbn[c]       = sc;
        sbn[128 + c] = beta[c] - mean * sc;
    }
    __syncthreads();

    const int l  = threadIdx.x & 63;
    const int w  = threadIdx.x >> 6;
    const int r0 = blockIdx.x * 64 + w * 16;
    const int arow = r0 + (l & 15);
    const int kl = (l >> 4) * 8;
    f32x4 acc[8];
    #pragma unroll
    for (int ct = 0; ct < 8; ++ct) acc[ct] = (f32x4){0.f, 0.f, 0.f, 0.f};
    const bool aok = (arow < M);
    #pragma unroll
    for (int ks = 0; ks < 8; ++ks) {
        bf16x8 a = {0, 0, 0, 0, 0, 0, 0, 0};
        if (aok) {
            if (ks < 4) {
                int k0 = ks * 32 + kl;
                bf16x8 raw = *(const bf16x8*)(A1 + (size_t)arow * 128 + k0);
                #pragma unroll
                for (int j = 0; j < 8; ++j)
                    a[j] = (short)f2bf(bf2f((unsigned short)raw[j]) * sbn[k0 + j] + sbn[128 + k0 + j]);
            } else {
                a = loadA_f32(A2 + (size_t)arow * 128 + (ks - 4) * 32 + kl);
            }
        }
        #pragma unroll
        for (int ct = 0; ct < 8; ++ct) {
            bf16x8 b = *(const bf16x8*)(Bp1 + (((ks * 8 + ct) * 64 + l) << 3));
            acc[ct] = __builtin_amdgcn_mfma_f32_16x16x32_bf16(a, b, acc[ct], 0, 0, 0);
        }
    }
    {
        const int lr0 = w * 16 + (l >> 4) * 4;
        const int oc  = l & 15;
        #pragma unroll
        for (int ct = 0; ct < 8; ++ct) {
            int col = ct * 16 + oc;
            float bv = b1[col];
            #pragma unroll
            for (int r = 0; r < 4; ++r)
                h[lr0 + r][col] = f2bf(fmaxf(acc[ct][r] + bv, 0.f));
        }
    }
    __syncthreads();
    #pragma unroll
    for (int ct = 0; ct < 8; ++ct) acc[ct] = (f32x4){0.f, 0.f, 0.f, 0.f};
    const int lrow = w * 16 + (l & 15);
    #pragma unroll
    for (int ks = 0; ks < 4; ++ks) {
        bf16x8 a = *(const bf16x8*)&h[lrow][ks * 32 + kl];
        #pragma unroll
        for (int ct = 0; ct < 8; ++ct) {
            bf16x8 b = *(const bf16x8*)(Bp2 + (((ks * 8 + ct) * 64 + l) << 3));
            acc[ct] = __builtin_amdgcn_mfma_f32_16x16x32_bf16(a, b, acc[ct], 0, 0, 0);
        }
    }
    const int orow = r0 + (l >> 4) * 4;
    const int oc   = l & 15;
    #pragma unroll
    for (int ct = 0; ct < 8; ++ct) {
        int col = ct * 16 + oc;
        float bv = b2[col];
        #pragma unroll
        for (int r = 0; r < 4; ++r)
            if (orow + r < M)
                out[(size_t)(orow + r) * 128 + col] = acc[ct][r] + bv;
    }
}

// ---------------------------------------------------------------------------
// launch
// ---------------------------------------------------------------------------
extern "C" void kernel_launch(void* const* d_in, const int* in_sizes, int n_in,
                              void* d_out, int out_size, void* d_ws, size_t ws_size,
                              hipStream_t stream)
{
    const float* left  = (const float*)d_in[0];
    const float* right = (const float*)d_in[1];
    const float* ef    = (const float*)d_in[2];
    const int*   esrc  = (const int*)d_in[3];
    const int*   edst  = (const int*)d_in[4];
    const float* Wq    = (const float*)d_in[5];
    const float* Wk    = (const float*)d_in[6];
    const float* Wv    = (const float*)d_in[7];
    const float* Wke   = (const float*)d_in[8];
    const float* Wve   = (const float*)d_in[9];
    const float* Wout  = (const float*)d_in[10];
    const float* gamma = (const float*)d_in[11];
    const float* beta  = (const float*)d_in[12];
    const float* W1    = (const float*)d_in[13];
    const float* b1    = (const float*)d_in[14];
    const float* W2    = (const float*)d_in[15];
    const float* b2    = (const float*)d_in[16];
    float* out = (float*)d_out;

    char* ws = (char*)d_ws;
    float* stats   = (float*)(ws + 0);                         //      1,024
    int*   cursors = (int*)  (ws + 1024);                      //     80,000
    unsigned short* Bp     = (unsigned short*)(ws + 81024);    //    229,376
    unsigned short* qproj  = (unsigned short*)(ws + 310400);   //  5,120,000
    unsigned short* kvproj = (unsigned short*)(ws + 5430400);  //  2,560,000
    unsigned short* agg    = (unsigned short*)(ws + 7990400);  //  5,120,000
    uint4* rec     = (uint4*)(ws + 13110400);                  // 17,920,000 (20000*56*16)
    unsigned short* out0   = (unsigned short*)(ws + 13110400); //  aliases rec (dead after attn)
    // total: 31,030,400 bytes

    pack_init<<<528, 256, 0, stream>>>(Wq, Wk, Wv, Wout, W2, W1, Bp, cursors, stats);

    scatter_qkv<<<904, 256, 0, stream>>>(edst, esrc, (const float4*)ef, cursors, rec,
                                         right, left, Bp, Bp + 16384, Bp + 32768,
                                         qproj, kvproj);

    attn_kernel<<<2048, 256, 0, stream>>>(qproj, kvproj, rec, cursors, Wke, Wve, agg);

    gemm_out0<<<(N_RIGHTC + 63) / 64, 256, 0, stream>>>(agg, Bp + 49152, out0, stats, N_RIGHTC);

    gemm_tail<<<(N_RIGHTC + 63) / 64, 256, 0, stream>>>(out0, right, stats, gamma, beta,
                                                        Bp + 81920, b1, Bp + 65536, b2,
                                                        out, N_RIGHTC);
}